// Round 1
// baseline (1271.387 us; speedup 1.0000x reference)
//
#include <hip/hip_runtime.h>
#include <hip/hip_bf16.h>
#include <cstdint>

typedef unsigned short u16;
typedef unsigned int u32;
typedef __attribute__((ext_vector_type(8))) short bf16x8;
typedef __attribute__((ext_vector_type(4))) float f32x4;
typedef __attribute__((ext_vector_type(4))) unsigned int u32x4;

#define HIDDEN 4096
#define NH 32
#define NKV 8
#define HD 128
#define QSZ 4096
#define KVSZ 1024
#define QKV_N 6144
#define SEQ 2048
#define NB 2
#define NTOK (NB*SEQ)
#define ATT_SCALE 0.08838834764831845f
#define LN_EPS 1e-5f

__device__ __forceinline__ u16 f2bf(float f) {
  union { float f; u32 u; } a; a.f = f;
  u32 r = a.u + 0x7fffu + ((a.u >> 16) & 1u);
  return (u16)(r >> 16);
}
__device__ __forceinline__ float bf2f(u16 h) {
  union { u32 u; float f; } a; a.u = ((u32)h) << 16;
  return a.f;
}

__device__ __forceinline__ void gload_lds16(const void* g, void* l) {
  __builtin_amdgcn_global_load_lds(
      (const __attribute__((address_space(1))) void*)g,
      (__attribute__((address_space(3))) void*)l,
      16, 0, 0);
}

// ---------------- stage 0a: f32 -> bf16 flat convert (8 elems/thread) -------
__global__ __launch_bounds__(256)
void conv_f32_bf16(const float* __restrict__ in, u16* __restrict__ out, int n8) {
  int i = blockIdx.x * 256 + threadIdx.x;
  if (i >= n8) return;
  const float4* p = (const float4*)in + (size_t)i * 2;
  float4 v0 = p[0], v1 = p[1];
  u32x4 o;
  o.x = (u32)f2bf(v0.x) | ((u32)f2bf(v0.y) << 16);
  o.y = (u32)f2bf(v0.z) | ((u32)f2bf(v0.w) << 16);
  o.z = (u32)f2bf(v1.x) | ((u32)f2bf(v1.y) << 16);
  o.w = (u32)f2bf(v1.z) | ((u32)f2bf(v1.w) << 16);
  ((u32x4*)out)[i] = o;
}

// ---------------- stage 0b: f32 [R][C] -> bf16 [C][R] transpose -------------
__global__ __launch_bounds__(256)
void transp_f32_bf16(const float* __restrict__ in, u16* __restrict__ out, int R, int C) {
  __shared__ float tile[32][33];
  int c0 = blockIdx.x << 5, r0 = blockIdx.y << 5;
  int tx = threadIdx.x & 31, ty = threadIdx.x >> 5; // 32 x 8
  #pragma unroll
  for (int j = 0; j < 32; j += 8)
    tile[ty + j][tx] = in[(long)(r0 + ty + j) * C + c0 + tx];
  __syncthreads();
  #pragma unroll
  for (int j = 0; j < 32; j += 8)
    out[(long)(c0 + ty + j) * R + r0 + tx] = f2bf(tile[tx][ty + j]);
}

// ---------------- GEMM: C[M][N] = A[M][K] * Bt[N][K]^T  (bf16 in, OutT out) --
// m97 structure: 128x128 tile, BK=32, 4 waves (2x2), global_load_lds width 16.
template<typename OutT>
__global__ __launch_bounds__(256)
void gemm_bt(const u16* __restrict__ A, const u16* __restrict__ Bt, OutT* __restrict__ C,
             int M, int N, int K) {
  __shared__ u16 As[128 * 32];
  __shared__ u16 Bs[128 * 32];
  const int t = threadIdx.x;
  const int lane = t & 63, wave = t >> 6;
  const int wm = wave >> 1, wn = wave & 1;
  const int bm = blockIdx.y, bn = blockIdx.x;
  f32x4 acc[4][4] = {};
  const int srow = t >> 2, schunk = t & 3;
  const u16* Ag = A + (long)(bm * 128 + srow) * K + schunk * 8;
  const u16* Bg = Bt + (long)(bn * 128 + srow) * K + schunk * 8;
  char* AsB = (char*)As + wave * 1024;  // wave-uniform LDS dest base
  char* BsB = (char*)Bs + wave * 1024;
  const int lrow = lane & 15;
  const int lkB = (lane >> 4) * 16;     // byte offset of this lane's 8-bf16 k-chunk

  for (int k0 = 0; k0 < K; k0 += 32) {
    __syncthreads();                    // prev iteration's reads done
    gload_lds16(Ag + k0, AsB);
    gload_lds16(Ag + 64 * (long)K + k0, AsB + 4096);
    gload_lds16(Bg + k0, BsB);
    gload_lds16(Bg + 64 * (long)K + k0, BsB + 4096);
    __syncthreads();                    // drains vmcnt before barrier
    bf16x8 a[4], b[4];
    #pragma unroll
    for (int i = 0; i < 4; ++i) {
      a[i] = *(const bf16x8*)((const char*)As + (wm * 64 + i * 16 + lrow) * 64 + lkB);
      b[i] = *(const bf16x8*)((const char*)Bs + (wn * 64 + i * 16 + lrow) * 64 + lkB);
    }
    #pragma unroll
    for (int i = 0; i < 4; ++i)
      #pragma unroll
      for (int j = 0; j < 4; ++j)
        acc[i][j] = __builtin_amdgcn_mfma_f32_16x16x32_bf16(a[i], b[j], acc[i][j], 0, 0, 0);
  }
  // epilogue: C/D layout col = lane&15, row = (lane>>4)*4 + reg
  const int r0 = bm * 128 + wm * 64 + (lane >> 4) * 4;
  const int c0 = bn * 128 + wn * 64 + lrow;
  #pragma unroll
  for (int i = 0; i < 4; ++i)
    #pragma unroll
    for (int j = 0; j < 4; ++j)
      #pragma unroll
      for (int r = 0; r < 4; ++r) {
        long row = r0 + i * 16 + r;
        long col = c0 + j * 16;
        float v = acc[i][j][r];
        if constexpr (sizeof(OutT) == 2) C[row * N + col] = f2bf(v);
        else                             C[row * N + col] = v;
      }
}

// ---------------- stage 2: headwise LN + RoPE(GPT-J) + scale + rearrange ----
__device__ __forceinline__ void ln_rope_head(const u16* __restrict__ src,
                                             const float* __restrict__ wgt,
                                             u16* __restrict__ dst,
                                             int lane, float sa, float ca, float scale) {
  u32 xr = *(const u32*)(src + 2 * lane);
  float x1 = bf2f((u16)(xr & 0xffffu)), x2 = bf2f((u16)(xr >> 16));
  float ssum = x1 + x2;
  #pragma unroll
  for (int off = 1; off < 64; off <<= 1) ssum += __shfl_xor(ssum, off);
  float mean = ssum * (1.0f / 128.0f);
  float e1 = x1 - mean, e2 = x2 - mean;
  float vv = e1 * e1 + e2 * e2;
  #pragma unroll
  for (int off = 1; off < 64; off <<= 1) vv += __shfl_xor(vv, off);
  float rstd = rsqrtf(vv * (1.0f / 128.0f) + LN_EPS);
  float y1 = e1 * rstd * wgt[2 * lane];
  float y2 = e2 * rstd * wgt[2 * lane + 1];
  float o1 = (y1 * ca - y2 * sa) * scale;
  float o2 = (y2 * ca + y1 * sa) * scale;
  *(u32*)(dst + 2 * lane) = (u32)f2bf(o1) | ((u32)f2bf(o2) << 16);
}

__global__ __launch_bounds__(512)
void ln_rope(const u16* __restrict__ qkv, const int* __restrict__ pos,
             const float* __restrict__ qw, const float* __restrict__ kw,
             u16* __restrict__ qo, u16* __restrict__ ko, u16* __restrict__ vo) {
  const int s = blockIdx.x, b = blockIdx.y;
  const int t = threadIdx.x, lane = t & 63, w = t >> 6; // 8 waves
  const long base = (long)(b * SEQ + s) * QKV_N;
  const int p = pos[b * SEQ + s];
  const float expo = (float)(2 * lane) * (1.0f / 128.0f);
  const float inv_freq = exp2f(-expo * 13.287712379549449f); // log2(10000)
  float sa, ca;
  sincosf((float)p * inv_freq, &sa, &ca);
  // Q heads: wave w handles heads w, w+8, w+16, w+24
  #pragma unroll
  for (int hh = 0; hh < 4; ++hh) {
    int h = w + hh * 8;
    ln_rope_head(qkv + base + h * HD, qw + h * HD,
                 qo + (((long)b * NH + h) * SEQ + s) * HD, lane, sa, ca, ATT_SCALE);
  }
  // K heads: wave w handles kv head w
  ln_rope_head(qkv + base + QSZ + w * HD, kw + w * HD,
               ko + (((long)b * NKV + w) * SEQ + s) * HD, lane, sa, ca, 1.0f);
  // V: plain copy/rearrange (2 elems/thread)
  int off = t * 2;
  int vh = off >> 7, vd = off & 127;
  u32 vv = *(const u32*)(qkv + base + QSZ + KVSZ + off);
  *(u32*)(vo + (((long)b * NKV + vh) * SEQ + s) * HD + vd) = vv;
}

// ---------------- stage 3: causal GQA flash attention -----------------------
// grid (S/64, H, B); block 256 = 4 waves; wave w owns q rows [qb+16w, qb+16w+16)
__global__ __launch_bounds__(256)
void flash_attn(const u16* __restrict__ Qg, const u16* __restrict__ Kg,
                const u16* __restrict__ Vg, u16* __restrict__ Og) {
  const int qt = blockIdx.x, h = blockIdx.y, b = blockIdx.z;
  const int kvh = h >> 2;
  const int t = threadIdx.x, lane = t & 63, w = t >> 6;
  const int qb = qt * 64, wq0 = qb + w * 16;
  __shared__ u16 Vt[128 * 32];     // V^T tile: [d][kv]
  __shared__ u16 Ps[4][16 * 32];   // per-wave P tile: [q][kv]
  const u16* Qbase = Qg + (((long)b * NH + h) * SEQ + wq0 + (lane & 15)) * HD;
  bf16x8 qf[4];
  #pragma unroll
  for (int ks = 0; ks < 4; ++ks)
    qf[ks] = *(const bf16x8*)(Qbase + ks * 32 + (lane >> 4) * 8);
  f32x4 acc[8];
  #pragma unroll
  for (int i = 0; i < 8; ++i) acc[i] = (f32x4){0.f, 0.f, 0.f, 0.f};
  float m[4] = {-1e30f, -1e30f, -1e30f, -1e30f};
  float l[4] = {0.f, 0.f, 0.f, 0.f};
  const u16* Kbase = Kg + ((long)b * NKV + kvh) * SEQ * HD;
  const u16* Vbase = Vg + ((long)b * NKV + kvh) * SEQ * HD;
  const int ntiles = (qb + 64) >> 5;
  u16* ps = &Ps[w][0];

  for (int kt = 0; kt < ntiles; ++kt) {
    const int kv0 = kt * 32;
    __syncthreads();                       // protect Vt/Ps from prev-iter reads
    { // stage V transposed: 256 threads, 2 passes of 16 kv rows
      const int ch = t & 15;
      #pragma unroll
      for (int pp = 0; pp < 2; ++pp) {
        int kv = pp * 16 + (t >> 4);
        bf16x8 vv = *(const bf16x8*)(Vbase + (long)(kv0 + kv) * HD + ch * 8);
        #pragma unroll
        for (int j = 0; j < 8; ++j)
          Vt[(ch * 8 + j) * 32 + kv] = (u16)vv[j];
      }
    }
    // QK^T: S[16q][32kv] as two 16x16 tiles; K frags straight from global (L2)
    f32x4 s0 = {0.f, 0.f, 0.f, 0.f}, s1 = {0.f, 0.f, 0.f, 0.f};
    #pragma unroll
    for (int ks = 0; ks < 4; ++ks) {
      const u16* kp = Kbase + (long)(kv0 + (lane & 15)) * HD + ks * 32 + (lane >> 4) * 8;
      bf16x8 kf0 = *(const bf16x8*)kp;
      bf16x8 kf1 = *(const bf16x8*)(kp + 16 * HD);
      s0 = __builtin_amdgcn_mfma_f32_16x16x32_bf16(qf[ks], kf0, s0, 0, 0, 0);
      s1 = __builtin_amdgcn_mfma_f32_16x16x32_bf16(qf[ks], kf1, s1, 0, 0, 0);
    }
    if (kv0 + 31 > wq0) { // causal mask (kv > q)
      #pragma unroll
      for (int r = 0; r < 4; ++r) {
        int q = wq0 + (lane >> 4) * 4 + r;
        int kva = kv0 + (lane & 15);
        if (kva > q)      s0[r] = -1e30f;
        if (kva + 16 > q) s1[r] = -1e30f;
      }
    }
    // online softmax (rows live across 16 lanes: reduce over lane&15)
    float p0[4], p1[4];
    #pragma unroll
    for (int r = 0; r < 4; ++r) {
      float mx = fmaxf(s0[r], s1[r]);
      #pragma unroll
      for (int off = 1; off < 16; off <<= 1) mx = fmaxf(mx, __shfl_xor(mx, off));
      float mn = fmaxf(m[r], mx);
      float sc = __expf(m[r] - mn);
      p0[r] = __expf(s0[r] - mn);
      p1[r] = __expf(s1[r] - mn);
      float rs = p0[r] + p1[r];
      #pragma unroll
      for (int off = 1; off < 16; off <<= 1) rs += __shfl_xor(rs, off);
      l[r] = l[r] * sc + rs;
      m[r] = mn;
      #pragma unroll
      for (int dt = 0; dt < 8; ++dt) acc[dt][r] *= sc;
    }
    // P -> LDS (re-fragment for PV A-operand)
    #pragma unroll
    for (int r = 0; r < 4; ++r) {
      int q = (lane >> 4) * 4 + r;
      ps[q * 32 + (lane & 15)] = f2bf(p0[r]);
      ps[q * 32 + 16 + (lane & 15)] = f2bf(p1[r]);
    }
    __syncthreads();                        // Vt staged + Ps written
    bf16x8 pf = *(const bf16x8*)((const char*)ps + (lane & 15) * 64 + (lane >> 4) * 16);
    #pragma unroll
    for (int dt = 0; dt < 8; ++dt) {
      bf16x8 vf = *(const bf16x8*)((const char*)Vt + (dt * 16 + (lane & 15)) * 64 + (lane >> 4) * 16);
      acc[dt] = __builtin_amdgcn_mfma_f32_16x16x32_bf16(pf, vf, acc[dt], 0, 0, 0);
    }
  }
  // epilogue: normalize and write O (token-major [B*S][4096] bf16)
  #pragma unroll
  for (int r = 0; r < 4; ++r) {
    float inv = 1.0f / l[r];
    long row = (long)b * SEQ + wq0 + (lane >> 4) * 4 + r;
    u16* ob = Og + row * QSZ + h * HD + (lane & 15);
    #pragma unroll
    for (int dt = 0; dt < 8; ++dt)
      ob[dt * 16] = f2bf(acc[dt][r] * inv);
  }
}

// ---------------- launch -----------------------------------------------------
extern "C" void kernel_launch(void* const* d_in, const int* in_sizes, int n_in,
                              void* d_out, int out_size, void* d_ws, size_t ws_size,
                              hipStream_t stream) {
  const int*   positions = (const int*)d_in[0];
  const float* hidden    = (const float*)d_in[1];
  const float* Wqkv      = (const float*)d_in[2];
  const float* qnw       = (const float*)d_in[3];
  const float* knw       = (const float*)d_in[4];
  const float* Wo        = (const float*)d_in[5];
  float* out = (float*)d_out;
  char* ws = (char*)d_ws;
  const size_t MB = 1024 * 1024;
  // aliased workspace plan (128 MB total), safe by stream ordering:
  u16* hbf   = (u16*)(ws + 0);        // 32MB: hidden bf16 (dead after gemm1)
  u16* WqkvT = (u16*)(ws + 32 * MB);  // 48MB: Wqkv^T bf16 (dead after gemm1)
  u16* qkvb  = (u16*)(ws + 80 * MB);  // 48MB: qkv bf16 (dead after ln_rope)
  u16* q_arr = (u16*)(ws + 0);        // 32MB (aliases hbf)
  u16* k_arr = (u16*)(ws + 32 * MB);  //  8MB (aliases WqkvT[0:8M])
  u16* v_arr = (u16*)(ws + 40 * MB);  //  8MB (aliases WqkvT[8M:16M])
  u16* WoT   = (u16*)(ws + 48 * MB);  // 32MB (aliases WqkvT[16M:48M])
  u16* Oarr  = (u16*)(ws + 80 * MB);  // 32MB (aliases qkvb[0:32M])

  conv_f32_bf16<<<dim3(NTOK * HIDDEN / 8 / 256), 256, 0, stream>>>(hidden, hbf, NTOK * HIDDEN / 8);
  transp_f32_bf16<<<dim3(QKV_N / 32, HIDDEN / 32), 256, 0, stream>>>(Wqkv, WqkvT, HIDDEN, QKV_N);
  gemm_bt<u16><<<dim3(QKV_N / 128, NTOK / 128), 256, 0, stream>>>(hbf, WqkvT, qkvb, NTOK, QKV_N, HIDDEN);
  ln_rope<<<dim3(SEQ, NB), 512, 0, stream>>>(qkvb, positions, qnw, knw, q_arr, k_arr, v_arr);
  transp_f32_bf16<<<dim3(HIDDEN / 32, QSZ / 32), 256, 0, stream>>>(Wo, WoT, QSZ, HIDDEN);
  flash_attn<<<dim3(SEQ / 64, NH, NB), 256, 0, stream>>>(q_arr, k_arr, v_arr, Oarr);
  gemm_bt<float><<<dim3(HIDDEN / 128, NTOK / 128), 256, 0, stream>>>(Oarr, WoT, out, NTOK, HIDDEN, QSZ);
}

// Round 2
// 674.120 us; speedup vs baseline: 1.8860x; 1.8860x over previous
//
#include <hip/hip_runtime.h>
#include <hip/hip_bf16.h>
#include <cstdint>

typedef unsigned short u16;
typedef unsigned int u32;
typedef __attribute__((ext_vector_type(8))) short bf16x8;
typedef __attribute__((ext_vector_type(4))) float f32x4;
typedef __attribute__((ext_vector_type(16))) float f32x16;
typedef __attribute__((ext_vector_type(4))) unsigned int u32x4;

#define HIDDEN 4096
#define NH 32
#define NKV 8
#define HD 128
#define QSZ 4096
#define KVSZ 1024
#define QKV_N 6144
#define SEQ 2048
#define NB 2
#define NTOK (NB*SEQ)
#define ATT_SCALE 0.08838834764831845f
#define LOG2E 1.4426950408889634f
#define LN_EPS 1e-5f
#define THRD 12.0f   // defer-max threshold (log2 domain)

__device__ __forceinline__ u16 f2bf(float f) {
  union { float f; u32 u; } a; a.f = f;
  u32 r = a.u + 0x7fffu + ((a.u >> 16) & 1u);
  return (u16)(r >> 16);
}
__device__ __forceinline__ float bf2f(u16 h) {
  union { u32 u; float f; } a; a.u = ((u32)h) << 16;
  return a.f;
}

__device__ __forceinline__ void gload_lds16(const void* g, void* l) {
  __builtin_amdgcn_global_load_lds(
      (const __attribute__((address_space(1))) void*)g,
      (__attribute__((address_space(3))) void*)l,
      16, 0, 0);
}

// ---------------- stage 0a: f32 -> bf16 flat convert (8 elems/thread) -------
__global__ __launch_bounds__(256)
void conv_f32_bf16(const float* __restrict__ in, u16* __restrict__ out, int n8) {
  int i = blockIdx.x * 256 + threadIdx.x;
  if (i >= n8) return;
  const float4* p = (const float4*)in + (size_t)i * 2;
  float4 v0 = p[0], v1 = p[1];
  u32x4 o;
  o.x = (u32)f2bf(v0.x) | ((u32)f2bf(v0.y) << 16);
  o.y = (u32)f2bf(v0.z) | ((u32)f2bf(v0.w) << 16);
  o.z = (u32)f2bf(v1.x) | ((u32)f2bf(v1.y) << 16);
  o.w = (u32)f2bf(v1.z) | ((u32)f2bf(v1.w) << 16);
  ((u32x4*)out)[i] = o;
}

// ---------------- stage 0b: f32 [R][C] -> bf16 [C][R] transpose -------------
__global__ __launch_bounds__(256)
void transp_f32_bf16(const float* __restrict__ in, u16* __restrict__ out, int R, int C) {
  __shared__ float tile[32][33];
  int c0 = blockIdx.x << 5, r0 = blockIdx.y << 5;
  int tx = threadIdx.x & 31, ty = threadIdx.x >> 5; // 32 x 8
  #pragma unroll
  for (int j = 0; j < 32; j += 8)
    tile[ty + j][tx] = in[(long)(r0 + ty + j) * C + c0 + tx];
  __syncthreads();
  #pragma unroll
  for (int j = 0; j < 32; j += 8)
    out[(long)(c0 + ty + j) * R + r0 + tx] = f2bf(tile[tx][ty + j]);
}

// ---------------- GEMM: C[M][N] = A[M][K] * Bt[N][K]^T  (bf16 in, OutT out) --
template<typename OutT>
__global__ __launch_bounds__(256)
void gemm_bt(const u16* __restrict__ A, const u16* __restrict__ Bt, OutT* __restrict__ C,
             int M, int N, int K) {
  __shared__ u16 As[128 * 32];
  __shared__ u16 Bs[128 * 32];
  const int t = threadIdx.x;
  const int lane = t & 63, wave = t >> 6;
  const int wm = wave >> 1, wn = wave & 1;
  const int bm = blockIdx.y, bn = blockIdx.x;
  f32x4 acc[4][4] = {};
  const int srow = t >> 2, schunk = t & 3;
  const u16* Ag = A + (long)(bm * 128 + srow) * K + schunk * 8;
  const u16* Bg = Bt + (long)(bn * 128 + srow) * K + schunk * 8;
  char* AsB = (char*)As + wave * 1024;
  char* BsB = (char*)Bs + wave * 1024;
  const int lrow = lane & 15;
  const int lkB = (lane >> 4) * 16;

  for (int k0 = 0; k0 < K; k0 += 32) {
    __syncthreads();
    gload_lds16(Ag + k0, AsB);
    gload_lds16(Ag + 64 * (long)K + k0, AsB + 4096);
    gload_lds16(Bg + k0, BsB);
    gload_lds16(Bg + 64 * (long)K + k0, BsB + 4096);
    __syncthreads();
    bf16x8 a[4], b[4];
    #pragma unroll
    for (int i = 0; i < 4; ++i) {
      a[i] = *(const bf16x8*)((const char*)As + (wm * 64 + i * 16 + lrow) * 64 + lkB);
      b[i] = *(const bf16x8*)((const char*)Bs + (wn * 64 + i * 16 + lrow) * 64 + lkB);
    }
    #pragma unroll
    for (int i = 0; i < 4; ++i)
      #pragma unroll
      for (int j = 0; j < 4; ++j)
        acc[i][j] = __builtin_amdgcn_mfma_f32_16x16x32_bf16(a[i], b[j], acc[i][j], 0, 0, 0);
  }
  const int r0 = bm * 128 + wm * 64 + (lane >> 4) * 4;
  const int c0 = bn * 128 + wn * 64 + lrow;
  #pragma unroll
  for (int i = 0; i < 4; ++i)
    #pragma unroll
    for (int j = 0; j < 4; ++j)
      #pragma unroll
      for (int r = 0; r < 4; ++r) {
        long row = r0 + i * 16 + r;
        long col = c0 + j * 16;
        float v = acc[i][j][r];
        if constexpr (sizeof(OutT) == 2) C[row * N + col] = f2bf(v);
        else                             C[row * N + col] = v;
      }
}

// ---------------- stage 2: headwise LN + RoPE(GPT-J) + scale ----------------
__device__ __forceinline__ void ln_rope_head(const u16* __restrict__ src,
                                             const float* __restrict__ wgt,
                                             u16* __restrict__ dst,
                                             int lane, float sa, float ca, float scale) {
  u32 xr = *(const u32*)(src + 2 * lane);
  float x1 = bf2f((u16)(xr & 0xffffu)), x2 = bf2f((u16)(xr >> 16));
  float ssum = x1 + x2;
  #pragma unroll
  for (int off = 1; off < 64; off <<= 1) ssum += __shfl_xor(ssum, off);
  float mean = ssum * (1.0f / 128.0f);
  float e1 = x1 - mean, e2 = x2 - mean;
  float vv = e1 * e1 + e2 * e2;
  #pragma unroll
  for (int off = 1; off < 64; off <<= 1) vv += __shfl_xor(vv, off);
  float rstd = rsqrtf(vv * (1.0f / 128.0f) + LN_EPS);
  float y1 = e1 * rstd * wgt[2 * lane];
  float y2 = e2 * rstd * wgt[2 * lane + 1];
  float o1 = (y1 * ca - y2 * sa) * scale;
  float o2 = (y2 * ca + y1 * sa) * scale;
  *(u32*)(dst + 2 * lane) = (u32)f2bf(o1) | ((u32)f2bf(o2) << 16);
}

__global__ __launch_bounds__(512)
void ln_rope(const u16* __restrict__ qkv, const int* __restrict__ pos,
             const float* __restrict__ qw, const float* __restrict__ kw,
             u16* __restrict__ qo, u16* __restrict__ ko) {
  const int s = blockIdx.x, b = blockIdx.y;
  const int t = threadIdx.x, lane = t & 63, w = t >> 6; // 8 waves
  const long base = (long)(b * SEQ + s) * QKV_N;
  const int p = pos[b * SEQ + s];
  const float expo = (float)(2 * lane) * (1.0f / 128.0f);
  const float inv_freq = exp2f(-expo * 13.287712379549449f); // log2(10000)
  float sa, ca;
  sincosf((float)p * inv_freq, &sa, &ca);
  #pragma unroll
  for (int hh = 0; hh < 4; ++hh) {
    int h = w + hh * 8;
    ln_rope_head(qkv + base + h * HD, qw + h * HD,
                 qo + (((long)b * NH + h) * SEQ + s) * HD, lane, sa, ca,
                 ATT_SCALE * LOG2E);  // fold log2e: flash uses exp2
  }
  ln_rope_head(qkv + base + QSZ + w * HD, kw + w * HD,
               ko + (((long)b * NKV + w) * SEQ + s) * HD, lane, sa, ca, 1.0f);
}

// ---------------- stage 2b: V slice of qkv -> V^T [b][kvh][d][S] ------------
__global__ __launch_bounds__(256)
void v_transp(const u16* __restrict__ qkv, u16* __restrict__ vt) {
  __shared__ u16 tile[32][33];
  int s0 = blockIdx.x * 32, d0 = blockIdx.y * 32;
  int bk = blockIdx.z;                 // b*NKV + kvh
  int b = bk >> 3, kvh = bk & 7;
  int tx = threadIdx.x & 31, ty = threadIdx.x >> 5;
  const u16* src = qkv + ((long)(b * SEQ) + s0) * QKV_N + QSZ + KVSZ + kvh * HD + d0;
  #pragma unroll
  for (int j = 0; j < 32; j += 8)
    tile[ty + j][tx] = src[(long)(ty + j) * QKV_N + tx];
  __syncthreads();
  u16* dst = vt + (((long)bk) * HD + d0) * SEQ + s0;
  #pragma unroll
  for (int j = 0; j < 32; j += 8)
    dst[(long)(ty + j) * SEQ + tx] = tile[tx][ty + j];
}

// ---------------- stage 3: causal GQA flash attention (8-wave 32x32) --------
// grid 512 blocks x 512 thr; block covers 256 q rows; wave w: rows [wq0,wq0+32)
// Swapped QK^T: S^T = mfma(K, Q) -> lane owns q column (lane&31), partner lane^32.
// K LDS [kv][128d], V^T LDS [d][64kv]; both XOR-chunk-swizzled via pre-swizzled
// global source (global_load_lds dest is linear lane*16).
__global__ __launch_bounds__(512, 2)
void flash_attn2(const u16* __restrict__ Qg, const u16* __restrict__ Kg,
                 const u16* __restrict__ Vtg, u16* __restrict__ Og) {
  const int lin = blockIdx.x;
  const int b = lin >> 8;
  const int rem = lin & 255;
  const int h = rem >> 3;
  const int q3 = rem & 7;
  const int qt = b ? (7 - q3) : q3;   // pair heavy+light across dispatch rounds
  const int kvh = h >> 2;
  const int t = threadIdx.x, lane = t & 63, w = t >> 6;
  const int hh = lane >> 5, l31 = lane & 31;
  const int wq0 = qt * 256 + w * 32;
  const int q = wq0 + l31;

  __shared__ u16 Klds[2][64 * 128];   // 2 x 16KB
  __shared__ u16 Vlds[2][128 * 64];   // 2 x 16KB  (total exactly 64KB)

  // Q frags: lane holds Q[q][ks*16 + hh*8 .. +8], ks=0..7
  const u16* Qbase = Qg + (((long)b * NH + h) * SEQ + q) * HD + hh * 8;
  bf16x8 qf[8];
  #pragma unroll
  for (int ks = 0; ks < 8; ++ks) qf[ks] = *(const bf16x8*)(Qbase + ks * 16);

  f32x16 o[4];
  #pragma unroll
  for (int i = 0; i < 4; ++i)
    #pragma unroll
    for (int r = 0; r < 16; ++r) o[i][r] = 0.f;
  float m = -1e30f, l = 0.f;

  const u16* Kbase = Kg + ((long)b * NKV + kvh) * (long)SEQ * HD;   // [kv][128]
  const u16* Vtbase = Vtg + ((long)b * NKV + kvh) * (long)HD * SEQ; // [d][2048]
  const int nt = qt * 4 + 4;

  auto STAGE = [&](int buf, int kt) {
    const int kv0 = kt * 64;
    #pragma unroll
    for (int i = 0; i < 2; ++i) {   // K: 1024 chunks of 16B
      int c = t + i * 512;
      int kv = c >> 4, cc = c & 15;
      int cl = (cc & 8) | ((cc ^ kv) & 7);      // inverse swizzle on source
      gload_lds16(Kbase + (long)(kv0 + kv) * HD + cl * 8,
                  (char*)(&Klds[buf][0]) + (i * 512 + w * 64) * 16);
    }
    #pragma unroll
    for (int i = 0; i < 2; ++i) {   // V^T: 1024 chunks of 16B
      int c = t + i * 512;
      int d = c >> 3, cc = c & 7;
      int cl = cc ^ (d & 7);
      gload_lds16(Vtbase + (long)d * SEQ + kv0 + cl * 8,
                  (char*)(&Vlds[buf][0]) + (i * 512 + w * 64) * 16);
    }
  };

  STAGE(0, 0);
  __syncthreads();
  int cur = 0;
  for (int kt = 0; kt < nt; ++kt) {
    const int kv0 = kt * 64;
    if (kt + 1 < nt) STAGE(cur ^ 1, kt + 1);   // prefetch next tile (other buf)
    if (kv0 <= wq0 + 31) {                      // wave-relevant tile
      const char* Kb = (const char*)(&Klds[cur][0]);
      const char* Vb = (const char*)(&Vlds[cur][0]);
      // ---- QK^T (swapped): st[tt] = K_tile x Q^T, lane col = q
      f32x16 st[2];
      #pragma unroll
      for (int tt = 0; tt < 2; ++tt)
        #pragma unroll
        for (int r = 0; r < 16; ++r) st[tt][r] = 0.f;
      __builtin_amdgcn_s_setprio(1);
      #pragma unroll
      for (int tt = 0; tt < 2; ++tt) {
        if (kv0 + tt * 32 <= wq0 + 31) {
          #pragma unroll
          for (int ks = 0; ks < 8; ++ks) {
            int ch = ks * 2 + hh;
            int pc = (ch & 8) | ((ch ^ l31) & 7);   // swizzled read
            bf16x8 kf = *(const bf16x8*)(Kb + (tt * 32 + l31) * 256 + pc * 16);
            st[tt] = __builtin_amdgcn_mfma_f32_32x32x16_bf16(kf, qf[ks], st[tt], 0, 0, 0);
          }
        }
      }
      __builtin_amdgcn_s_setprio(0);
      // ---- causal mask (kv row > q col). Fully-masked halves (skipped above,
      // st==0) are also covered since all their kva > q.
      if (kv0 + 63 > wq0) {
        #pragma unroll
        for (int tt = 0; tt < 2; ++tt)
          #pragma unroll
          for (int r = 0; r < 16; ++r) {
            int kva = kv0 + tt * 32 + (r & 3) + 8 * (r >> 2) + 4 * hh;
            if (kva > q) st[tt][r] = -1e30f;
          }
      }
      // ---- online softmax, exp2 domain, lane-local (4 partial trees)
      float p0 = -1e30f, p1 = -1e30f, p2 = -1e30f, p3 = -1e30f;
      #pragma unroll
      for (int tt = 0; tt < 2; ++tt)
        #pragma unroll
        for (int r = 0; r < 16; r += 4) {
          p0 = fmaxf(p0, st[tt][r]);
          p1 = fmaxf(p1, st[tt][r + 1]);
          p2 = fmaxf(p2, st[tt][r + 2]);
          p3 = fmaxf(p3, st[tt][r + 3]);
        }
      float mx = fmaxf(fmaxf(p0, p1), fmaxf(p2, p3));
      mx = fmaxf(mx, __shfl_xor(mx, 32));
      if (!__all(mx - m <= THRD)) {            // defer-max (T13)
        float mn = fmaxf(m, mx);
        float sc = exp2f(m - mn);
        m = mn;
        float scr[16];
        #pragma unroll
        for (int r = 0; r < 16; ++r)
          scr[r] = __shfl(sc, (r & 3) + 8 * (r >> 2) + 4 * hh);
        #pragma unroll
        for (int db = 0; db < 4; ++db)
          #pragma unroll
          for (int r = 0; r < 16; ++r) o[db][r] *= scr[r];
        l *= sc;
      }
      float s0 = 0.f, s1 = 0.f, s2 = 0.f, s3 = 0.f;
      #pragma unroll
      for (int tt = 0; tt < 2; ++tt)
        #pragma unroll
        for (int r = 0; r < 16; r += 4) {
          float e0 = exp2f(st[tt][r] - m);
          float e1 = exp2f(st[tt][r + 1] - m);
          float e2 = exp2f(st[tt][r + 2] - m);
          float e3 = exp2f(st[tt][r + 3] - m);
          st[tt][r] = e0; st[tt][r + 1] = e1; st[tt][r + 2] = e2; st[tt][r + 3] = e3;
          s0 += e0; s1 += e1; s2 += e2; s3 += e3;
        }
      float rs = (s0 + s1) + (s2 + s3);
      rs += __shfl_xor(rs, 32);
      l += rs;
      // ---- pack P^T -> PA A-frags (half-exchange via shfl_xor(.,32))
      bf16x8 pa[4];
      #pragma unroll
      for (int k4 = 0; k4 < 4; ++k4) {
        int s8 = (k4 & 1) * 8, tt = k4 >> 1;
        u32 x0 = (u32)f2bf(st[tt][s8 + 0]) | ((u32)f2bf(st[tt][s8 + 1]) << 16);
        u32 x1 = (u32)f2bf(st[tt][s8 + 2]) | ((u32)f2bf(st[tt][s8 + 3]) << 16);
        u32 y0 = (u32)f2bf(st[tt][s8 + 4]) | ((u32)f2bf(st[tt][s8 + 5]) << 16);
        u32 y1 = (u32)f2bf(st[tt][s8 + 6]) | ((u32)f2bf(st[tt][s8 + 7]) << 16);
        u32 x0s = (u32)__shfl_xor((int)x0, 32), x1s = (u32)__shfl_xor((int)x1, 32);
        u32 y0s = (u32)__shfl_xor((int)y0, 32), y1s = (u32)__shfl_xor((int)y1, 32);
        union { u32 u[4]; bf16x8 v; } pk;
        pk.u[0] = hh ? y0s : x0;   // kv +0,1 of this lane's k-slice
        pk.u[1] = hh ? y1s : x1;   // kv +2,3
        pk.u[2] = hh ? y0 : x0s;   // kv +4,5
        pk.u[3] = hh ? y1 : x1s;   // kv +6,7
        pa[k4] = pk.v;
      }
      // ---- PV: O[q][d] += P x V
      __builtin_amdgcn_s_setprio(1);
      #pragma unroll
      for (int k4 = 0; k4 < 4; ++k4)
        #pragma unroll
        for (int db = 0; db < 4; ++db) {
          int ch = k4 * 2 + hh;
          int pcc = ch ^ (l31 & 7);
          bf16x8 vf = *(const bf16x8*)(Vb + (db * 32 + l31) * 128 + pcc * 16);
          o[db] = __builtin_amdgcn_mfma_f32_32x32x16_bf16(pa[k4], vf, o[db], 0, 0, 0);
        }
      __builtin_amdgcn_s_setprio(0);
    }
    __syncthreads();   // drains vmcnt -> next buf ready; protects buf reuse
    cur ^= 1;
  }
  // ---- epilogue: O row-stats via wave gather, write token-major bf16
  float linv = 1.0f / l;
  float li[16];
  #pragma unroll
  for (int r = 0; r < 16; ++r)
    li[r] = __shfl(linv, (r & 3) + 8 * (r >> 2) + 4 * hh);
  #pragma unroll
  for (int db = 0; db < 4; ++db)
    #pragma unroll
    for (int r = 0; r < 16; ++r) {
      int qr = wq0 + (r & 3) + 8 * (r >> 2) + 4 * hh;
      Og[((long)b * SEQ + qr) * QSZ + h * HD + db * 32 + l31] = f2bf(o[db][r] * li[r]);
    }
}

// ---------------- launch -----------------------------------------------------
extern "C" void kernel_launch(void* const* d_in, const int* in_sizes, int n_in,
                              void* d_out, int out_size, void* d_ws, size_t ws_size,
                              hipStream_t stream) {
  const int*   positions = (const int*)d_in[0];
  const float* hidden    = (const float*)d_in[1];
  const float* Wqkv      = (const float*)d_in[2];
  const float* qnw       = (const float*)d_in[3];
  const float* knw       = (const float*)d_in[4];
  const float* Wo        = (const float*)d_in[5];
  float* out = (float*)d_out;
  char* ws = (char*)d_ws;
  const size_t MB = 1024 * 1024;
  u16* hbf   = (u16*)(ws + 0);        // 32MB: hidden bf16 (dead after gemm1)
  u16* WqkvT = (u16*)(ws + 32 * MB);  // 48MB: Wqkv^T bf16 (dead after gemm1)
  u16* qkvb  = (u16*)(ws + 80 * MB);  // 48MB: qkv bf16 (dead after ln_rope+v_transp)
  u16* q_arr = (u16*)(ws + 0);        // 32MB (aliases hbf)
  u16* k_arr = (u16*)(ws + 32 * MB);  //  8MB (aliases WqkvT[0:8M])
  u16* vt_arr= (u16*)(ws + 40 * MB);  //  8MB V^T [b][kvh][d][S]
  u16* WoT   = (u16*)(ws + 48 * MB);  // 32MB (aliases WqkvT[16M:48M])
  u16* Oarr  = (u16*)(ws + 80 * MB);  // 32MB (aliases qkvb[0:32M])

  conv_f32_bf16<<<dim3(NTOK * HIDDEN / 8 / 256), 256, 0, stream>>>(hidden, hbf, NTOK * HIDDEN / 8);
  transp_f32_bf16<<<dim3(QKV_N / 32, HIDDEN / 32), 256, 0, stream>>>(Wqkv, WqkvT, HIDDEN, QKV_N);
  gemm_bt<u16><<<dim3(QKV_N / 128, NTOK / 128), 256, 0, stream>>>(hbf, WqkvT, qkvb, NTOK, QKV_N, HIDDEN);
  ln_rope<<<dim3(SEQ, NB), 512, 0, stream>>>(qkvb, positions, qnw, knw, q_arr, k_arr);
  v_transp<<<dim3(SEQ / 32, HD / 32, NB * NKV), 256, 0, stream>>>(qkvb, vt_arr);
  transp_f32_bf16<<<dim3(HIDDEN / 32, QSZ / 32), 256, 0, stream>>>(Wo, WoT, QSZ, HIDDEN);
  flash_attn2<<<dim3(512), 512, 0, stream>>>(q_arr, k_arr, vt_arr, Oarr);
  gemm_bt<float><<<dim3(HIDDEN / 128, NTOK / 128), 256, 0, stream>>>(Oarr, WoT, out, NTOK, HIDDEN, QSZ);
}

// Round 3
// 618.672 us; speedup vs baseline: 2.0550x; 1.0896x over previous
//
#include <hip/hip_runtime.h>
#include <hip/hip_bf16.h>
#include <cstdint>

typedef unsigned short u16;
typedef unsigned int u32;
typedef __attribute__((ext_vector_type(8))) short bf16x8;
typedef __attribute__((ext_vector_type(4))) float f32x4;
typedef __attribute__((ext_vector_type(16))) float f32x16;
typedef __attribute__((ext_vector_type(4))) unsigned int u32x4;

#define HIDDEN 4096
#define NH 32
#define NKV 8
#define HD 128
#define QSZ 4096
#define KVSZ 1024
#define QKV_N 6144
#define SEQ 2048
#define NB 2
#define NTOK (NB*SEQ)
#define ATT_SCALE 0.08838834764831845f
#define LOG2E 1.4426950408889634f
#define LN_EPS 1e-5f
#define THRD 12.0f   // defer-max threshold (log2 domain)

__device__ __forceinline__ u16 f2bf(float f) {
  union { float f; u32 u; } a; a.f = f;
  u32 r = a.u + 0x7fffu + ((a.u >> 16) & 1u);
  return (u16)(r >> 16);
}
__device__ __forceinline__ float bf2f(u16 h) {
  union { u32 u; float f; } a; a.u = ((u32)h) << 16;
  return a.f;
}

__device__ __forceinline__ void gload_lds16(const void* g, void* l) {
  __builtin_amdgcn_global_load_lds(
      (const __attribute__((address_space(1))) void*)g,
      (__attribute__((address_space(3))) void*)l,
      16, 0, 0);
}

// ---------------- stage 0a: f32 -> bf16 flat convert (8 elems/thread) -------
__global__ __launch_bounds__(256)
void conv_f32_bf16(const float* __restrict__ in, u16* __restrict__ out, int n8) {
  int i = blockIdx.x * 256 + threadIdx.x;
  if (i >= n8) return;
  const float4* p = (const float4*)in + (size_t)i * 2;
  float4 v0 = p[0], v1 = p[1];
  u32x4 o;
  o.x = (u32)f2bf(v0.x) | ((u32)f2bf(v0.y) << 16);
  o.y = (u32)f2bf(v0.z) | ((u32)f2bf(v0.w) << 16);
  o.z = (u32)f2bf(v1.x) | ((u32)f2bf(v1.y) << 16);
  o.w = (u32)f2bf(v1.z) | ((u32)f2bf(v1.w) << 16);
  ((u32x4*)out)[i] = o;
}

// ---------------- stage 0b: f32 [R][C] -> bf16 [C][R] transpose -------------
__global__ __launch_bounds__(256)
void transp_f32_bf16(const float* __restrict__ in, u16* __restrict__ out, int R, int C) {
  __shared__ float tile[32][33];
  int c0 = blockIdx.x << 5, r0 = blockIdx.y << 5;
  int tx = threadIdx.x & 31, ty = threadIdx.x >> 5; // 32 x 8
  #pragma unroll
  for (int j = 0; j < 32; j += 8)
    tile[ty + j][tx] = in[(long)(r0 + ty + j) * C + c0 + tx];
  __syncthreads();
  #pragma unroll
  for (int j = 0; j < 32; j += 8)
    out[(long)(c0 + ty + j) * R + r0 + tx] = f2bf(tile[tx][ty + j]);
}

// ---------------- GEMM v2: C[M][N] = A[M][K] * Bt[N][K]^T  (bf16 in) --------
// BM=128 BN=256 BK=64; 8 waves (2x4) of 64x64 wave-tiles; mfma 32x32x16.
// 3-buffer LDS pipeline (3 x 48KB), 2 phases/K-tile, counted vmcnt(6),
// XOR-chunk swizzle p = c ^ (row&7) staged via pre-swizzled global source.
template<typename OutT>
__global__ __launch_bounds__(512, 2)
void gemm_bt2(const u16* __restrict__ A, const u16* __restrict__ Bt,
              OutT* __restrict__ C, int N, int K) {
  extern __shared__ char smem[];            // 3 * 49152 bytes
  const int t = threadIdx.x;
  const int lane = t & 63, w = t >> 6;
  const int wr = w >> 2, wc = w & 3;
  const int l31 = lane & 31, l7 = lane & 7, g2 = lane >> 5;

  // XCD-aware bijective block swizzle (gridDim.x divisible by 8)
  const int nbn = N >> 8;
  const int cpx = gridDim.x >> 3;
  const int wg = (blockIdx.x & 7) * cpx + (blockIdx.x >> 3);
  const int bm = wg / nbn, bn = wg - bm * nbn;

  // staging source pointers: LDS chunk ci -> row r=ci>>3, phys chunk p=ci&7,
  // logical chunk c = p ^ (r&7); source = row_base*K + k0 + c*8
  const int ciA0 = t, ciA1 = t + 512;
  const u16* AgS0 = A + (long)(bm * 128 + (ciA0 >> 3)) * K + (((ciA0 & 7) ^ ((ciA0 >> 3) & 7)) << 3);
  const u16* AgS1 = A + (long)(bm * 128 + (ciA1 >> 3)) * K + (((ciA1 & 7) ^ ((ciA1 >> 3) & 7)) << 3);
  const u16* BgS0;
  const u16* BgS1;
  const u16* BgS2;
  const u16* BgS3;
  {
    int ci0 = t, ci1 = t + 512, ci2 = t + 1024, ci3 = t + 1536;
    BgS0 = Bt + (long)(bn * 256 + (ci0 >> 3)) * K + (((ci0 & 7) ^ ((ci0 >> 3) & 7)) << 3);
    BgS1 = Bt + (long)(bn * 256 + (ci1 >> 3)) * K + (((ci1 & 7) ^ ((ci1 >> 3) & 7)) << 3);
    BgS2 = Bt + (long)(bn * 256 + (ci2 >> 3)) * K + (((ci2 & 7) ^ ((ci2 >> 3) & 7)) << 3);
    BgS3 = Bt + (long)(bn * 256 + (ci3 >> 3)) * K + (((ci3 & 7) ^ ((ci3 >> 3) & 7)) << 3);
  }
  // LDS dest offsets (wave-uniform base; HW adds lane*16)
  const int dA0 = (w * 64) * 16;
  const int dA1 = (512 + w * 64) * 16;
  const int dB0 = 16384 + (w * 64) * 16;
  const int dB1 = 16384 + (512 + w * 64) * 16;
  const int dB2 = 16384 + (1024 + w * 64) * 16;
  const int dB3 = 16384 + (1536 + w * 64) * 16;

  // fragment read bases: A-frag(mf,kk'): row = wr*64+mf*32+l31, chunk c=kk'*2+g2
  const int arow0 = (wr * 64 + l31) * 128;
  const int brow0 = 16384 + (wc * 64 + l31) * 128;

  f32x16 acc[2][2];
  #pragma unroll
  for (int i = 0; i < 2; ++i)
    #pragma unroll
    for (int j = 0; j < 2; ++j)
      #pragma unroll
      for (int r = 0; r < 16; ++r) acc[i][j][r] = 0.f;

  const int nt = K >> 6;
  char* cbase = smem;
  char* nbase = smem + 49152;
  char* sbase = smem + 98304;

  // prologue: stage tiles 0 (buf0) and 1 (buf1); vmcnt(6) leaves tile1's B+A..
  gload_lds16(AgS0, cbase + dA0);  gload_lds16(AgS1, cbase + dA1);
  gload_lds16(BgS0, cbase + dB0);  gload_lds16(BgS1, cbase + dB1);
  gload_lds16(BgS2, cbase + dB2);  gload_lds16(BgS3, cbase + dB3);
  gload_lds16(AgS0 + 64, nbase + dA0);  gload_lds16(AgS1 + 64, nbase + dA1);
  gload_lds16(BgS0 + 64, nbase + dB0);  gload_lds16(BgS1 + 64, nbase + dB1);
  gload_lds16(BgS2 + 64, nbase + dB2);  gload_lds16(BgS3 + 64, nbase + dB3);
  asm volatile("s_waitcnt vmcnt(6)" ::: "memory");
  __builtin_amdgcn_s_barrier();
  __builtin_amdgcn_sched_barrier(0);

  for (int tt = 0; tt < nt; ++tt) {
    const long sk = (long)((tt + 2 < nt) ? (tt + 2) : (nt - 1)) * 64; // clamp keeps vmcnt uniform
    // ================= phase 0 (kk' = 0,1) =================
    bf16x8 aF[2][2], bF[2][2];
    #pragma unroll
    for (int kk = 0; kk < 2; ++kk) {
      const int pcb = ((kk * 2 + g2) ^ l7) * 16;
      #pragma unroll
      for (int mf = 0; mf < 2; ++mf)
        aF[kk][mf] = *(const bf16x8*)(cbase + arow0 + mf * 32 * 128 + pcb);
      #pragma unroll
      for (int nf = 0; nf < 2; ++nf)
        bF[kk][nf] = *(const bf16x8*)(cbase + brow0 + nf * 32 * 128 + pcb);
    }
    gload_lds16(AgS0 + sk, sbase + dA0);
    gload_lds16(AgS1 + sk, sbase + dA1);
    __builtin_amdgcn_s_barrier();
    __builtin_amdgcn_sched_barrier(0);
    __builtin_amdgcn_s_setprio(1);
    #pragma unroll
    for (int kk = 0; kk < 2; ++kk)
      #pragma unroll
      for (int mf = 0; mf < 2; ++mf)
        #pragma unroll
        for (int nf = 0; nf < 2; ++nf)
          acc[mf][nf] = __builtin_amdgcn_mfma_f32_32x32x16_bf16(aF[kk][mf], bF[kk][nf], acc[mf][nf], 0, 0, 0);
    __builtin_amdgcn_s_setprio(0);
    __builtin_amdgcn_sched_barrier(0);
    __builtin_amdgcn_s_barrier();
    __builtin_amdgcn_sched_barrier(0);
    // ================= phase 1 (kk' = 2,3) =================
    #pragma unroll
    for (int kk = 0; kk < 2; ++kk) {
      const int pcb = (((kk + 2) * 2 + g2) ^ l7) * 16;
      #pragma unroll
      for (int mf = 0; mf < 2; ++mf)
        aF[kk][mf] = *(const bf16x8*)(cbase + arow0 + mf * 32 * 128 + pcb);
      #pragma unroll
      for (int nf = 0; nf < 2; ++nf)
        bF[kk][nf] = *(const bf16x8*)(cbase + brow0 + nf * 32 * 128 + pcb);
    }
    gload_lds16(BgS0 + sk, sbase + dB0);
    gload_lds16(BgS1 + sk, sbase + dB1);
    gload_lds16(BgS2 + sk, sbase + dB2);
    gload_lds16(BgS3 + sk, sbase + dB3);
    asm volatile("s_waitcnt vmcnt(6)" ::: "memory");  // tile t+1 fully landed; t+2 in flight
    __builtin_amdgcn_s_barrier();
    __builtin_amdgcn_sched_barrier(0);
    __builtin_amdgcn_s_setprio(1);
    #pragma unroll
    for (int kk = 0; kk < 2; ++kk)
      #pragma unroll
      for (int mf = 0; mf < 2; ++mf)
        #pragma unroll
        for (int nf = 0; nf < 2; ++nf)
          acc[mf][nf] = __builtin_amdgcn_mfma_f32_32x32x16_bf16(aF[kk][mf], bF[kk][nf], acc[mf][nf], 0, 0, 0);
    __builtin_amdgcn_s_setprio(0);
    __builtin_amdgcn_sched_barrier(0);
    __builtin_amdgcn_s_barrier();
    __builtin_amdgcn_sched_barrier(0);
    // rotate buffers: cur <- next <- stage <- cur
    char* tmp = cbase; cbase = nbase; nbase = sbase; sbase = tmp;
  }

  // epilogue: C/D layout col = lane&31, row = (r&3) + 8*(r>>2) + 4*(lane>>5)
  #pragma unroll
  for (int mf = 0; mf < 2; ++mf)
    #pragma unroll
    for (int nf = 0; nf < 2; ++nf)
      #pragma unroll
      for (int r = 0; r < 16; ++r) {
        long row = bm * 128 + wr * 64 + mf * 32 + (r & 3) + 8 * (r >> 2) + 4 * g2;
        long col = bn * 256 + wc * 64 + nf * 32 + l31;
        float v = acc[mf][nf][r];
        if constexpr (sizeof(OutT) == 2) C[row * N + col] = f2bf(v);
        else                             C[row * N + col] = v;
      }
}

// ---------------- stage 2: headwise LN + RoPE(GPT-J) + scale ----------------
__device__ __forceinline__ void ln_rope_head(const u16* __restrict__ src,
                                             const float* __restrict__ wgt,
                                             u16* __restrict__ dst,
                                             int lane, float sa, float ca, float scale) {
  u32 xr = *(const u32*)(src + 2 * lane);
  float x1 = bf2f((u16)(xr & 0xffffu)), x2 = bf2f((u16)(xr >> 16));
  float ssum = x1 + x2;
  #pragma unroll
  for (int off = 1; off < 64; off <<= 1) ssum += __shfl_xor(ssum, off);
  float mean = ssum * (1.0f / 128.0f);
  float e1 = x1 - mean, e2 = x2 - mean;
  float vv = e1 * e1 + e2 * e2;
  #pragma unroll
  for (int off = 1; off < 64; off <<= 1) vv += __shfl_xor(vv, off);
  float rstd = rsqrtf(vv * (1.0f / 128.0f) + LN_EPS);
  float y1 = e1 * rstd * wgt[2 * lane];
  float y2 = e2 * rstd * wgt[2 * lane + 1];
  float o1 = (y1 * ca - y2 * sa) * scale;
  float o2 = (y2 * ca + y1 * sa) * scale;
  *(u32*)(dst + 2 * lane) = (u32)f2bf(o1) | ((u32)f2bf(o2) << 16);
}

__global__ __launch_bounds__(512)
void ln_rope(const u16* __restrict__ qkv, const int* __restrict__ pos,
             const float* __restrict__ qw, const float* __restrict__ kw,
             u16* __restrict__ qo, u16* __restrict__ ko) {
  const int s = blockIdx.x, b = blockIdx.y;
  const int t = threadIdx.x, lane = t & 63, w = t >> 6; // 8 waves
  const long base = (long)(b * SEQ + s) * QKV_N;
  const int p = pos[b * SEQ + s];
  const float expo = (float)(2 * lane) * (1.0f / 128.0f);
  const float inv_freq = exp2f(-expo * 13.287712379549449f); // log2(10000)
  float sa, ca;
  sincosf((float)p * inv_freq, &sa, &ca);
  #pragma unroll
  for (int hh = 0; hh < 4; ++hh) {
    int h = w + hh * 8;
    ln_rope_head(qkv + base + h * HD, qw + h * HD,
                 qo + (((long)b * NH + h) * SEQ + s) * HD, lane, sa, ca,
                 ATT_SCALE * LOG2E);  // fold log2e: flash uses exp2
  }
  ln_rope_head(qkv + base + QSZ + w * HD, kw + w * HD,
               ko + (((long)b * NKV + w) * SEQ + s) * HD, lane, sa, ca, 1.0f);
}

// ---------------- stage 2b: V slice of qkv -> V^T [b][kvh][d][S] ------------
__global__ __launch_bounds__(256)
void v_transp(const u16* __restrict__ qkv, u16* __restrict__ vt) {
  __shared__ u16 tile[32][33];
  int s0 = blockIdx.x * 32, d0 = blockIdx.y * 32;
  int bk = blockIdx.z;                 // b*NKV + kvh
  int b = bk >> 3, kvh = bk & 7;
  int tx = threadIdx.x & 31, ty = threadIdx.x >> 5;
  const u16* src = qkv + ((long)(b * SEQ) + s0) * QKV_N + QSZ + KVSZ + kvh * HD + d0;
  #pragma unroll
  for (int j = 0; j < 32; j += 8)
    tile[ty + j][tx] = src[(long)(ty + j) * QKV_N + tx];
  __syncthreads();
  u16* dst = vt + (((long)bk) * HD + d0) * SEQ + s0;
  #pragma unroll
  for (int j = 0; j < 32; j += 8)
    dst[(long)(ty + j) * SEQ + tx] = tile[tx][ty + j];
}

// ---------------- stage 3: causal GQA flash attention (8-wave 32x32) --------
__global__ __launch_bounds__(512, 2)
void flash_attn2(const u16* __restrict__ Qg, const u16* __restrict__ Kg,
                 const u16* __restrict__ Vtg, u16* __restrict__ Og) {
  const int lin = blockIdx.x;
  const int b = lin >> 8;
  const int rem = lin & 255;
  const int h = rem >> 3;
  const int q3 = rem & 7;
  const int qt = b ? (7 - q3) : q3;   // pair heavy+light across dispatch rounds
  const int kvh = h >> 2;
  const int t = threadIdx.x, lane = t & 63, w = t >> 6;
  const int hh = lane >> 5, l31 = lane & 31;
  const int wq0 = qt * 256 + w * 32;
  const int q = wq0 + l31;

  __shared__ u16 Klds[2][64 * 128];   // 2 x 16KB
  __shared__ u16 Vlds[2][128 * 64];   // 2 x 16KB  (total exactly 64KB)

  const u16* Qbase = Qg + (((long)b * NH + h) * SEQ + q) * HD + hh * 8;
  bf16x8 qf[8];
  #pragma unroll
  for (int ks = 0; ks < 8; ++ks) qf[ks] = *(const bf16x8*)(Qbase + ks * 16);

  f32x16 o[4];
  #pragma unroll
  for (int i = 0; i < 4; ++i)
    #pragma unroll
    for (int r = 0; r < 16; ++r) o[i][r] = 0.f;
  float m = -1e30f, l = 0.f;

  const u16* Kbase = Kg + ((long)b * NKV + kvh) * (long)SEQ * HD;   // [kv][128]
  const u16* Vtbase = Vtg + ((long)b * NKV + kvh) * (long)HD * SEQ; // [d][2048]
  const int nt = qt * 4 + 4;

  auto STAGE = [&](int buf, int kt) {
    const int kv0 = kt * 64;
    #pragma unroll
    for (int i = 0; i < 2; ++i) {   // K: 1024 chunks of 16B
      int c = t + i * 512;
      int kv = c >> 4, cc = c & 15;
      int cl = (cc & 8) | ((cc ^ kv) & 7);      // inverse swizzle on source
      gload_lds16(Kbase + (long)(kv0 + kv) * HD + cl * 8,
                  (char*)(&Klds[buf][0]) + (i * 512 + w * 64) * 16);
    }
    #pragma unroll
    for (int i = 0; i < 2; ++i) {   // V^T: 1024 chunks of 16B
      int c = t + i * 512;
      int d = c >> 3, cc = c & 7;
      int cl = cc ^ (d & 7);
      gload_lds16(Vtbase + (long)d * SEQ + kv0 + cl * 8,
                  (char*)(&Vlds[buf][0]) + (i * 512 + w * 64) * 16);
    }
  };

  STAGE(0, 0);
  __syncthreads();
  int cur = 0;
  for (int kt = 0; kt < nt; ++kt) {
    const int kv0 = kt * 64;
    if (kt + 1 < nt) STAGE(cur ^ 1, kt + 1);   // prefetch next tile (other buf)
    if (kv0 <= wq0 + 31) {                      // wave-relevant tile
      const char* Kb = (const char*)(&Klds[cur][0]);
      const char* Vb = (const char*)(&Vlds[cur][0]);
      f32x16 st[2];
      #pragma unroll
      for (int tt = 0; tt < 2; ++tt)
        #pragma unroll
        for (int r = 0; r < 16; ++r) st[tt][r] = 0.f;
      __builtin_amdgcn_s_setprio(1);
      #pragma unroll
      for (int tt = 0; tt < 2; ++tt) {
        if (kv0 + tt * 32 <= wq0 + 31) {
          #pragma unroll
          for (int ks = 0; ks < 8; ++ks) {
            int ch = ks * 2 + hh;
            int pc = (ch & 8) | ((ch ^ l31) & 7);   // swizzled read
            bf16x8 kf = *(const bf16x8*)(Kb + (tt * 32 + l31) * 256 + pc * 16);
            st[tt] = __builtin_amdgcn_mfma_f32_32x32x16_bf16(kf, qf[ks], st[tt], 0, 0, 0);
          }
        }
      }
      __builtin_amdgcn_s_setprio(0);
      if (kv0 + 63 > wq0) {
        #pragma unroll
        for (int tt = 0; tt < 2; ++tt)
          #pragma unroll
          for (int r = 0; r < 16; ++r) {
            int kva = kv0 + tt * 32 + (r & 3) + 8 * (r >> 2) + 4 * hh;
            if (kva > q) st[tt][r] = -1e30f;
          }
      }
      float p0 = -1e30f, p1 = -1e30f, p2 = -1e30f, p3 = -1e30f;
      #pragma unroll
      for (int tt = 0; tt < 2; ++tt)
        #pragma unroll
        for (int r = 0; r < 16; r += 4) {
          p0 = fmaxf(p0, st[tt][r]);
          p1 = fmaxf(p1, st[tt][r + 1]);
          p2 = fmaxf(p2, st[tt][r + 2]);
          p3 = fmaxf(p3, st[tt][r + 3]);
        }
      float mx = fmaxf(fmaxf(p0, p1), fmaxf(p2, p3));
      mx = fmaxf(mx, __shfl_xor(mx, 32));
      if (!__all(mx - m <= THRD)) {            // defer-max (T13)
        float mn = fmaxf(m, mx);
        float sc = exp2f(m - mn);
        m = mn;
        float scr[16];
        #pragma unroll
        for (int r = 0; r < 16; ++r)
          scr[r] = __shfl(sc, (r & 3) + 8 * (r >> 2) + 4 * hh);
        #pragma unroll
        for (int db = 0; db < 4; ++db)
          #pragma unroll
          for (int r = 0; r < 16; ++r) o[db][r] *= scr[r];
        l *= sc;
      }
      float s0 = 0.f, s1 = 0.f, s2 = 0.f, s3 = 0.f;
      #pragma unroll
      for (int tt = 0; tt < 2; ++tt)
        #pragma unroll
        for (int r = 0; r < 16; r += 4) {
          float e0 = exp2f(st[tt][r] - m);
          float e1 = exp2f(st[tt][r + 1] - m);
          float e2 = exp2f(st[tt][r + 2] - m);
          float e3 = exp2f(st[tt][r + 3] - m);
          st[tt][r] = e0; st[tt][r + 1] = e1; st[tt][r + 2] = e2; st[tt][r + 3] = e3;
          s0 += e0; s1 += e1; s2 += e2; s3 += e3;
        }
      float rs = (s0 + s1) + (s2 + s3);
      rs += __shfl_xor(rs, 32);
      l += rs;
      bf16x8 pa[4];
      #pragma unroll
      for (int k4 = 0; k4 < 4; ++k4) {
        int s8 = (k4 & 1) * 8, tt = k4 >> 1;
        u32 x0 = (u32)f2bf(st[tt][s8 + 0]) | ((u32)f2bf(st[tt][s8 + 1]) << 16);
        u32 x1 = (u32)f2bf(st[tt][s8 + 2]) | ((u32)f2bf(st[tt][s8 + 3]) << 16);
        u32 y0 = (u32)f2bf(st[tt][s8 + 4]) | ((u32)f2bf(st[tt][s8 + 5]) << 16);
        u32 y1 = (u32)f2bf(st[tt][s8 + 6]) | ((u32)f2bf(st[tt][s8 + 7]) << 16);
        u32 x0s = (u32)__shfl_xor((int)x0, 32), x1s = (u32)__shfl_xor((int)x1, 32);
        u32 y0s = (u32)__shfl_xor((int)y0, 32), y1s = (u32)__shfl_xor((int)y1, 32);
        union { u32 u[4]; bf16x8 v; } pk;
        pk.u[0] = hh ? y0s : x0;
        pk.u[1] = hh ? y1s : x1;
        pk.u[2] = hh ? y0 : x0s;
        pk.u[3] = hh ? y1 : x1s;
        pa[k4] = pk.v;
      }
      __builtin_amdgcn_s_setprio(1);
      #pragma unroll
      for (int k4 = 0; k4 < 4; ++k4)
        #pragma unroll
        for (int db = 0; db < 4; ++db) {
          int ch = k4 * 2 + hh;
          int pcc = ch ^ (l31 & 7);
          bf16x8 vf = *(const bf16x8*)(Vb + (db * 32 + l31) * 128 + pcc * 16);
          o[db] = __builtin_amdgcn_mfma_f32_32x32x16_bf16(pa[k4], vf, o[db], 0, 0, 0);
        }
      __builtin_amdgcn_s_setprio(0);
    }
    __syncthreads();
    cur ^= 1;
  }
  float linv = 1.0f / l;
  float li[16];
  #pragma unroll
  for (int r = 0; r < 16; ++r)
    li[r] = __shfl(linv, (r & 3) + 8 * (r >> 2) + 4 * hh);
  #pragma unroll
  for (int db = 0; db < 4; ++db)
    #pragma unroll
    for (int r = 0; r < 16; ++r) {
      int qr = wq0 + (r & 3) + 8 * (r >> 2) + 4 * hh;
      Og[((long)b * SEQ + qr) * QSZ + h * HD + db * 32 + l31] = f2bf(o[db][r] * li[r]);
    }
}

// ---------------- launch -----------------------------------------------------
extern "C" void kernel_launch(void* const* d_in, const int* in_sizes, int n_in,
                              void* d_out, int out_size, void* d_ws, size_t ws_size,
                              hipStream_t stream) {
  const int*   positions = (const int*)d_in[0];
  const float* hidden    = (const float*)d_in[1];
  const float* Wqkv      = (const float*)d_in[2];
  const float* qnw       = (const float*)d_in[3];
  const float* knw       = (const float*)d_in[4];
  const float* Wo        = (const float*)d_in[5];
  float* out = (float*)d_out;
  char* ws = (char*)d_ws;
  const size_t MB = 1024 * 1024;
  u16* hbf   = (u16*)(ws + 0);        // 32MB: hidden bf16 (dead after gemm1)
  u16* WqkvT = (u16*)(ws + 32 * MB);  // 48MB: Wqkv^T bf16 (dead after gemm1)
  u16* qkvb  = (u16*)(ws + 80 * MB);  // 48MB: qkv bf16 (dead after ln_rope+v_transp)
  u16* q_arr = (u16*)(ws + 0);        // 32MB (aliases hbf)
  u16* k_arr = (u16*)(ws + 32 * MB);  //  8MB (aliases WqkvT[0:8M])
  u16* vt_arr= (u16*)(ws + 40 * MB);  //  8MB V^T [b][kvh][d][S]
  u16* WoT   = (u16*)(ws + 48 * MB);  // 32MB (aliases WqkvT[16M:48M])
  u16* Oarr  = (u16*)(ws + 80 * MB);  // 32MB (aliases qkvb[0:32M])

  const int GEMM_LDS = 3 * 49152;     // 144 KB
  (void)hipFuncSetAttribute((const void*)&gemm_bt2<u16>,
        hipFuncAttributeMaxDynamicSharedMemorySize, GEMM_LDS);
  (void)hipFuncSetAttribute((const void*)&gemm_bt2<float>,
        hipFuncAttributeMaxDynamicSharedMemorySize, GEMM_LDS);

  conv_f32_bf16<<<dim3(NTOK * HIDDEN / 8 / 256), 256, 0, stream>>>(hidden, hbf, NTOK * HIDDEN / 8);
  transp_f32_bf16<<<dim3(QKV_N / 32, HIDDEN / 32), 256, 0, stream>>>(Wqkv, WqkvT, HIDDEN, QKV_N);
  gemm_bt2<u16><<<dim3((NTOK / 128) * (QKV_N / 256)), 512, GEMM_LDS, stream>>>(hbf, WqkvT, qkvb, QKV_N, HIDDEN);
  ln_rope<<<dim3(SEQ, NB), 512, 0, stream>>>(qkvb, positions, qnw, knw, q_arr, k_arr);
  v_transp<<<dim3(SEQ / 32, HD / 32, NB * NKV), 256, 0, stream>>>(qkvb, vt_arr);
  transp_f32_bf16<<<dim3(HIDDEN / 32, QSZ / 32), 256, 0, stream>>>(Wo, WoT, QSZ, HIDDEN);
  flash_attn2<<<dim3(512), 512, 0, stream>>>(q_arr, k_arr, vt_arr, Oarr);
  gemm_bt2<float><<<dim3((NTOK / 128) * (HIDDEN / 256)), 512, GEMM_LDS, stream>>>(Oarr, WoT, out, HIDDEN, QSZ);
}

// Round 4
// 581.203 us; speedup vs baseline: 2.1875x; 1.0645x over previous
//
#include <hip/hip_runtime.h>
#include <hip/hip_bf16.h>
#include <cstdint>

typedef unsigned short u16;
typedef unsigned int u32;
typedef __attribute__((ext_vector_type(8))) short bf16x8;
typedef __attribute__((ext_vector_type(4))) float f32x4;
typedef __attribute__((ext_vector_type(16))) float f32x16;
typedef __attribute__((ext_vector_type(4))) unsigned int u32x4;

#define HIDDEN 4096
#define NH 32
#define NKV 8
#define HD 128
#define QSZ 4096
#define KVSZ 1024
#define QKV_N 6144
#define SEQ 2048
#define NB 2
#define NTOK (NB*SEQ)
#define ATT_SCALE 0.08838834764831845f
#define LOG2E 1.4426950408889634f
#define LN_EPS 1e-5f
#define THRD 12.0f   // defer-max threshold (log2 domain)

__device__ __forceinline__ u16 f2bf(float f) {
  union { float f; u32 u; } a; a.f = f;
  u32 r = a.u + 0x7fffu + ((a.u >> 16) & 1u);
  return (u16)(r >> 16);
}
__device__ __forceinline__ float bf2f(u16 h) {
  union { u32 u; float f; } a; a.u = ((u32)h) << 16;
  return a.f;
}

__device__ __forceinline__ void gload_lds16(const void* g, void* l) {
  __builtin_amdgcn_global_load_lds(
      (const __attribute__((address_space(1))) void*)g,
      (__attribute__((address_space(3))) void*)l,
      16, 0, 0);
}

// ---------------- stage 0a: f32 -> bf16 flat convert (8 elems/thread) -------
__global__ __launch_bounds__(256)
void conv_f32_bf16(const float* __restrict__ in, u16* __restrict__ out, int n8) {
  int i = blockIdx.x * 256 + threadIdx.x;
  if (i >= n8) return;
  const float4* p = (const float4*)in + (size_t)i * 2;
  float4 v0 = p[0], v1 = p[1];
  u32x4 o;
  o.x = (u32)f2bf(v0.x) | ((u32)f2bf(v0.y) << 16);
  o.y = (u32)f2bf(v0.z) | ((u32)f2bf(v0.w) << 16);
  o.z = (u32)f2bf(v1.x) | ((u32)f2bf(v1.y) << 16);
  o.w = (u32)f2bf(v1.z) | ((u32)f2bf(v1.w) << 16);
  ((u32x4*)out)[i] = o;
}

// ---------------- stage 0b: f32 [R][C] -> bf16 [C][R] transpose -------------
__global__ __launch_bounds__(256)
void transp_f32_bf16(const float* __restrict__ in, u16* __restrict__ out, int R, int C) {
  __shared__ float tile[32][33];
  int c0 = blockIdx.x << 5, r0 = blockIdx.y << 5;
  int tx = threadIdx.x & 31, ty = threadIdx.x >> 5; // 32 x 8
  #pragma unroll
  for (int j = 0; j < 32; j += 8)
    tile[ty + j][tx] = in[(long)(r0 + ty + j) * C + c0 + tx];
  __syncthreads();
  #pragma unroll
  for (int j = 0; j < 32; j += 8)
    out[(long)(c0 + ty + j) * R + r0 + tx] = f2bf(tile[tx][ty + j]);
}

// ---------------- GEMM v3: C[M][N] = A[M][K] * Bt[N][K]^T  (bf16 in) --------
// BM=128 BN=256 BK=64; 8 waves (2x4) of 64x64 wave-tiles; mfma 32x32x16.
// 3-buffer LDS pipeline (3 x 48KB), ONE barrier + ONE counted vmcnt(6) per
// K-tile; ds_read(kk+1) pipelined under MFMA(kk); 2D grid (bn = x, natural
// round-robin -> each XCD sees few bn columns x all bm: B L2-resident).
template<typename OutT>
__global__ __launch_bounds__(512, 2)
void gemm_bt2(const u16* __restrict__ A, const u16* __restrict__ Bt,
              OutT* __restrict__ C, int N, int K) {
  extern __shared__ char smem[];            // 3 * 49152 bytes
  const int t = threadIdx.x;
  const int lane = t & 63, w = t >> 6;
  const int wr = w >> 2, wc = w & 3;
  const int l31 = lane & 31, l7 = lane & 7, g2 = lane >> 5;
  const int bm = blockIdx.y, bn = blockIdx.x;

  // staging source pointers: LDS chunk ci -> row r=ci>>3, phys chunk p=ci&7,
  // logical chunk c = p ^ (r&7); source = row_base*K + k0 + c*8
  const int ciA0 = t, ciA1 = t + 512;
  const u16* AgS0 = A + (long)(bm * 128 + (ciA0 >> 3)) * K + (((ciA0 & 7) ^ ((ciA0 >> 3) & 7)) << 3);
  const u16* AgS1 = A + (long)(bm * 128 + (ciA1 >> 3)) * K + (((ciA1 & 7) ^ ((ciA1 >> 3) & 7)) << 3);
  const u16* BgS0;
  const u16* BgS1;
  const u16* BgS2;
  const u16* BgS3;
  {
    int ci0 = t, ci1 = t + 512, ci2 = t + 1024, ci3 = t + 1536;
    BgS0 = Bt + (long)(bn * 256 + (ci0 >> 3)) * K + (((ci0 & 7) ^ ((ci0 >> 3) & 7)) << 3);
    BgS1 = Bt + (long)(bn * 256 + (ci1 >> 3)) * K + (((ci1 & 7) ^ ((ci1 >> 3) & 7)) << 3);
    BgS2 = Bt + (long)(bn * 256 + (ci2 >> 3)) * K + (((ci2 & 7) ^ ((ci2 >> 3) & 7)) << 3);
    BgS3 = Bt + (long)(bn * 256 + (ci3 >> 3)) * K + (((ci3 & 7) ^ ((ci3 >> 3) & 7)) << 3);
  }
  // LDS dest offsets (wave-uniform base; HW adds lane*16)
  const int dA0 = (w * 64) * 16;
  const int dA1 = (512 + w * 64) * 16;
  const int dB0 = 16384 + (w * 64) * 16;
  const int dB1 = 16384 + (512 + w * 64) * 16;
  const int dB2 = 16384 + (1024 + w * 64) * 16;
  const int dB3 = 16384 + (1536 + w * 64) * 16;

  // fragment read bases: A-frag(mf,kk'): row = wr*64+mf*32+l31, chunk c=kk'*2+g2
  const int arow0 = (wr * 64 + l31) * 128;
  const int brow0 = 16384 + (wc * 64 + l31) * 128;

  f32x16 acc[2][2];
  #pragma unroll
  for (int i = 0; i < 2; ++i)
    #pragma unroll
    for (int j = 0; j < 2; ++j)
      #pragma unroll
      for (int r = 0; r < 16; ++r) acc[i][j][r] = 0.f;

  const int nt = K >> 6;
  char* cbase = smem;
  char* nbase = smem + 49152;
  char* sbase = smem + 98304;

  // prologue: stage tiles 0 (buf0) and 1 (buf1); vmcnt(6) waits tile0 only
  gload_lds16(AgS0, cbase + dA0);  gload_lds16(AgS1, cbase + dA1);
  gload_lds16(BgS0, cbase + dB0);  gload_lds16(BgS1, cbase + dB1);
  gload_lds16(BgS2, cbase + dB2);  gload_lds16(BgS3, cbase + dB3);
  gload_lds16(AgS0 + 64, nbase + dA0);  gload_lds16(AgS1 + 64, nbase + dA1);
  gload_lds16(BgS0 + 64, nbase + dB0);  gload_lds16(BgS1 + 64, nbase + dB1);
  gload_lds16(BgS2 + 64, nbase + dB2);  gload_lds16(BgS3 + 64, nbase + dB3);
  asm volatile("s_waitcnt vmcnt(6)" ::: "memory");
  __builtin_amdgcn_s_barrier();
  __builtin_amdgcn_sched_barrier(0);

  #define READ_KK(dst, kkv) { \
    const int pcb = (((kkv) * 2 + g2) ^ l7) * 16; \
    dst[0] = *(const bf16x8*)(cbase + arow0 + pcb); \
    dst[1] = *(const bf16x8*)(cbase + arow0 + 32 * 128 + pcb); \
    dst[2] = *(const bf16x8*)(cbase + brow0 + pcb); \
    dst[3] = *(const bf16x8*)(cbase + brow0 + 32 * 128 + pcb); }
  #define MFMA_KK(src) { \
    __builtin_amdgcn_s_setprio(1); \
    acc[0][0] = __builtin_amdgcn_mfma_f32_32x32x16_bf16(src[0], src[2], acc[0][0], 0, 0, 0); \
    acc[0][1] = __builtin_amdgcn_mfma_f32_32x32x16_bf16(src[0], src[3], acc[0][1], 0, 0, 0); \
    acc[1][0] = __builtin_amdgcn_mfma_f32_32x32x16_bf16(src[1], src[2], acc[1][0], 0, 0, 0); \
    acc[1][1] = __builtin_amdgcn_mfma_f32_32x32x16_bf16(src[1], src[3], acc[1][1], 0, 0, 0); \
    __builtin_amdgcn_s_setprio(0); }

  for (int tt = 0; tt < nt; ++tt) {
    const long sk = (long)((tt + 2 < nt) ? (tt + 2) : (nt - 1)) * 64; // clamp keeps vmcnt uniform
    bf16x8 fA[4], fB[4];
    READ_KK(fA, 0);
    READ_KK(fB, 1);
    gload_lds16(AgS0 + sk, sbase + dA0);
    gload_lds16(AgS1 + sk, sbase + dA1);
    MFMA_KK(fA);
    READ_KK(fA, 2);
    gload_lds16(BgS0 + sk, sbase + dB0);
    gload_lds16(BgS1 + sk, sbase + dB1);
    MFMA_KK(fB);
    READ_KK(fB, 3);
    gload_lds16(BgS2 + sk, sbase + dB2);
    gload_lds16(BgS3 + sk, sbase + dB3);
    MFMA_KK(fA);
    MFMA_KK(fB);
    asm volatile("s_waitcnt vmcnt(6)" ::: "memory");  // tile t+1 fully landed; t+2 in flight
    __builtin_amdgcn_s_barrier();
    __builtin_amdgcn_sched_barrier(0);
    // rotate buffers: cur <- next <- stage <- cur
    char* tmp = cbase; cbase = nbase; nbase = sbase; sbase = tmp;
  }
  #undef READ_KK
  #undef MFMA_KK

  // epilogue: C/D layout col = lane&31, row = (r&3) + 8*(r>>2) + 4*(lane>>5)
  #pragma unroll
  for (int mf = 0; mf < 2; ++mf)
    #pragma unroll
    for (int nf = 0; nf < 2; ++nf)
      #pragma unroll
      for (int r = 0; r < 16; ++r) {
        long row = bm * 128 + wr * 64 + mf * 32 + (r & 3) + 8 * (r >> 2) + 4 * g2;
        long col = bn * 256 + wc * 64 + nf * 32 + l31;
        float v = acc[mf][nf][r];
        if constexpr (sizeof(OutT) == 2) C[row * N + col] = f2bf(v);
        else                             C[row * N + col] = v;
      }
}

// ---------------- stage 2: headwise LN + RoPE(GPT-J) + scale ----------------
__device__ __forceinline__ void ln_rope_head(const u16* __restrict__ src,
                                             const float* __restrict__ wgt,
                                             u16* __restrict__ dst,
                                             int lane, float sa, float ca, float scale) {
  u32 xr = *(const u32*)(src + 2 * lane);
  float x1 = bf2f((u16)(xr & 0xffffu)), x2 = bf2f((u16)(xr >> 16));
  float ssum = x1 + x2;
  #pragma unroll
  for (int off = 1; off < 64; off <<= 1) ssum += __shfl_xor(ssum, off);
  float mean = ssum * (1.0f / 128.0f);
  float e1 = x1 - mean, e2 = x2 - mean;
  float vv = e1 * e1 + e2 * e2;
  #pragma unroll
  for (int off = 1; off < 64; off <<= 1) vv += __shfl_xor(vv, off);
  float rstd = rsqrtf(vv * (1.0f / 128.0f) + LN_EPS);
  float y1 = e1 * rstd * wgt[2 * lane];
  float y2 = e2 * rstd * wgt[2 * lane + 1];
  float o1 = (y1 * ca - y2 * sa) * scale;
  float o2 = (y2 * ca + y1 * sa) * scale;
  *(u32*)(dst + 2 * lane) = (u32)f2bf(o1) | ((u32)f2bf(o2) << 16);
}

__global__ __launch_bounds__(512)
void ln_rope(const u16* __restrict__ qkv, const int* __restrict__ pos,
             const float* __restrict__ qw, const float* __restrict__ kw,
             u16* __restrict__ qo, u16* __restrict__ ko) {
  const int s = blockIdx.x, b = blockIdx.y;
  const int t = threadIdx.x, lane = t & 63, w = t >> 6; // 8 waves
  const long base = (long)(b * SEQ + s) * QKV_N;
  const int p = pos[b * SEQ + s];
  const float expo = (float)(2 * lane) * (1.0f / 128.0f);
  const float inv_freq = exp2f(-expo * 13.287712379549449f); // log2(10000)
  float sa, ca;
  sincosf((float)p * inv_freq, &sa, &ca);
  #pragma unroll
  for (int hh = 0; hh < 4; ++hh) {
    int h = w + hh * 8;
    ln_rope_head(qkv + base + h * HD, qw + h * HD,
                 qo + (((long)b * NH + h) * SEQ + s) * HD, lane, sa, ca,
                 ATT_SCALE * LOG2E);  // fold log2e: flash uses exp2
  }
  ln_rope_head(qkv + base + QSZ + w * HD, kw + w * HD,
               ko + (((long)b * NKV + w) * SEQ + s) * HD, lane, sa, ca, 1.0f);
}

// ---------------- stage 2b: V slice of qkv -> V^T [b][kvh][d][S] ------------
__global__ __launch_bounds__(256)
void v_transp(const u16* __restrict__ qkv, u16* __restrict__ vt) {
  __shared__ u16 tile[32][33];
  int s0 = blockIdx.x * 32, d0 = blockIdx.y * 32;
  int bk = blockIdx.z;                 // b*NKV + kvh
  int b = bk >> 3, kvh = bk & 7;
  int tx = threadIdx.x & 31, ty = threadIdx.x >> 5;
  const u16* src = qkv + ((long)(b * SEQ) + s0) * QKV_N + QSZ + KVSZ + kvh * HD + d0;
  #pragma unroll
  for (int j = 0; j < 32; j += 8)
    tile[ty + j][tx] = src[(long)(ty + j) * QKV_N + tx];
  __syncthreads();
  u16* dst = vt + (((long)bk) * HD + d0) * SEQ + s0;
  #pragma unroll
  for (int j = 0; j < 32; j += 8)
    dst[(long)(ty + j) * SEQ + tx] = tile[tx][ty + j];
}

// ---------------- stage 3: causal GQA flash attention (8-wave 32x32) --------
__global__ __launch_bounds__(512, 2)
void flash_attn2(const u16* __restrict__ Qg, const u16* __restrict__ Kg,
                 const u16* __restrict__ Vtg, u16* __restrict__ Og) {
  const int lin = blockIdx.x;
  const int b = lin >> 8;
  const int rem = lin & 255;
  const int h = rem >> 3;
  const int q3 = rem & 7;
  const int qt = b ? (7 - q3) : q3;   // pair heavy+light across dispatch rounds
  const int kvh = h >> 2;
  const int t = threadIdx.x, lane = t & 63, w = t >> 6;
  const int hh = lane >> 5, l31 = lane & 31;
  const int wq0 = qt * 256 + w * 32;
  const int q = wq0 + l31;

  __shared__ u16 Klds[2][64 * 128];   // 2 x 16KB
  __shared__ u16 Vlds[2][128 * 64];   // 2 x 16KB  (total exactly 64KB)

  const u16* Qbase = Qg + (((long)b * NH + h) * SEQ + q) * HD + hh * 8;
  bf16x8 qf[8];
  #pragma unroll
  for (int ks = 0; ks < 8; ++ks) qf[ks] = *(const bf16x8*)(Qbase + ks * 16);

  f32x16 o[4];
  #pragma unroll
  for (int i = 0; i < 4; ++i)
    #pragma unroll
    for (int r = 0; r < 16; ++r) o[i][r] = 0.f;
  float m = -1e30f, l = 0.f;

  const u16* Kbase = Kg + ((long)b * NKV + kvh) * (long)SEQ * HD;   // [kv][128]
  const u16* Vtbase = Vtg + ((long)b * NKV + kvh) * (long)HD * SEQ; // [d][2048]
  const int nt = qt * 4 + 4;

  auto STAGE = [&](int buf, int kt) {
    const int kv0 = kt * 64;
    #pragma unroll
    for (int i = 0; i < 2; ++i) {   // K: 1024 chunks of 16B
      int c = t + i * 512;
      int kv = c >> 4, cc = c & 15;
      int cl = (cc & 8) | ((cc ^ kv) & 7);      // inverse swizzle on source
      gload_lds16(Kbase + (long)(kv0 + kv) * HD + cl * 8,
                  (char*)(&Klds[buf][0]) + (i * 512 + w * 64) * 16);
    }
    #pragma unroll
    for (int i = 0; i < 2; ++i) {   // V^T: 1024 chunks of 16B
      int c = t + i * 512;
      int d = c >> 3, cc = c & 7;
      int cl = cc ^ (d & 7);
      gload_lds16(Vtbase + (long)d * SEQ + kv0 + cl * 8,
                  (char*)(&Vlds[buf][0]) + (i * 512 + w * 64) * 16);
    }
  };

  STAGE(0, 0);
  __syncthreads();
  int cur = 0;
  for (int kt = 0; kt < nt; ++kt) {
    const int kv0 = kt * 64;
    if (kt + 1 < nt) STAGE(cur ^ 1, kt + 1);   // prefetch next tile (other buf)
    if (kv0 <= wq0 + 31) {                      // wave-relevant tile
      const char* Kb = (const char*)(&Klds[cur][0]);
      const char* Vb = (const char*)(&Vlds[cur][0]);
      f32x16 st[2];
      #pragma unroll
      for (int tt = 0; tt < 2; ++tt)
        #pragma unroll
        for (int r = 0; r < 16; ++r) st[tt][r] = 0.f;
      __builtin_amdgcn_s_setprio(1);
      #pragma unroll
      for (int tt = 0; tt < 2; ++tt) {
        if (kv0 + tt * 32 <= wq0 + 31) {
          #pragma unroll
          for (int ks = 0; ks < 8; ++ks) {
            int ch = ks * 2 + hh;
            int pc = (ch & 8) | ((ch ^ l31) & 7);   // swizzled read
            bf16x8 kf = *(const bf16x8*)(Kb + (tt * 32 + l31) * 256 + pc * 16);
            st[tt] = __builtin_amdgcn_mfma_f32_32x32x16_bf16(kf, qf[ks], st[tt], 0, 0, 0);
          }
        }
      }
      __builtin_amdgcn_s_setprio(0);
      if (kv0 + 63 > wq0) {
        #pragma unroll
        for (int tt = 0; tt < 2; ++tt)
          #pragma unroll
          for (int r = 0; r < 16; ++r) {
            int kva = kv0 + tt * 32 + (r & 3) + 8 * (r >> 2) + 4 * hh;
            if (kva > q) st[tt][r] = -1e30f;
          }
      }
      float p0 = -1e30f, p1 = -1e30f, p2 = -1e30f, p3 = -1e30f;
      #pragma unroll
      for (int tt = 0; tt < 2; ++tt)
        #pragma unroll
        for (int r = 0; r < 16; r += 4) {
          p0 = fmaxf(p0, st[tt][r]);
          p1 = fmaxf(p1, st[tt][r + 1]);
          p2 = fmaxf(p2, st[tt][r + 2]);
          p3 = fmaxf(p3, st[tt][r + 3]);
        }
      float mx = fmaxf(fmaxf(p0, p1), fmaxf(p2, p3));
      mx = fmaxf(mx, __shfl_xor(mx, 32));
      if (!__all(mx - m <= THRD)) {            // defer-max (T13)
        float mn = fmaxf(m, mx);
        float sc = exp2f(m - mn);
        m = mn;
        float scr[16];
        #pragma unroll
        for (int r = 0; r < 16; ++r)
          scr[r] = __shfl(sc, (r & 3) + 8 * (r >> 2) + 4 * hh);
        #pragma unroll
        for (int db = 0; db < 4; ++db)
          #pragma unroll
          for (int r = 0; r < 16; ++r) o[db][r] *= scr[r];
        l *= sc;
      }
      float s0 = 0.f, s1 = 0.f, s2 = 0.f, s3 = 0.f;
      #pragma unroll
      for (int tt = 0; tt < 2; ++tt)
        #pragma unroll
        for (int r = 0; r < 16; r += 4) {
          float e0 = exp2f(st[tt][r] - m);
          float e1 = exp2f(st[tt][r + 1] - m);
          float e2 = exp2f(st[tt][r + 2] - m);
          float e3 = exp2f(st[tt][r + 3] - m);
          st[tt][r] = e0; st[tt][r + 1] = e1; st[tt][r + 2] = e2; st[tt][r + 3] = e3;
          s0 += e0; s1 += e1; s2 += e2; s3 += e3;
        }
      float rs = (s0 + s1) + (s2 + s3);
      rs += __shfl_xor(rs, 32);
      l += rs;
      bf16x8 pa[4];
      #pragma unroll
      for (int k4 = 0; k4 < 4; ++k4) {
        int s8 = (k4 & 1) * 8, tt = k4 >> 1;
        u32 x0 = (u32)f2bf(st[tt][s8 + 0]) | ((u32)f2bf(st[tt][s8 + 1]) << 16);
        u32 x1 = (u32)f2bf(st[tt][s8 + 2]) | ((u32)f2bf(st[tt][s8 + 3]) << 16);
        u32 y0 = (u32)f2bf(st[tt][s8 + 4]) | ((u32)f2bf(st[tt][s8 + 5]) << 16);
        u32 y1 = (u32)f2bf(st[tt][s8 + 6]) | ((u32)f2bf(st[tt][s8 + 7]) << 16);
        u32 x0s = (u32)__shfl_xor((int)x0, 32), x1s = (u32)__shfl_xor((int)x1, 32);
        u32 y0s = (u32)__shfl_xor((int)y0, 32), y1s = (u32)__shfl_xor((int)y1, 32);
        union { u32 u[4]; bf16x8 v; } pk;
        pk.u[0] = hh ? y0s : x0;
        pk.u[1] = hh ? y1s : x1;
        pk.u[2] = hh ? y0 : x0s;
        pk.u[3] = hh ? y1 : x1s;
        pa[k4] = pk.v;
      }
      __builtin_amdgcn_s_setprio(1);
      #pragma unroll
      for (int k4 = 0; k4 < 4; ++k4)
        #pragma unroll
        for (int db = 0; db < 4; ++db) {
          int ch = k4 * 2 + hh;
          int pcc = ch ^ (l31 & 7);
          bf16x8 vf = *(const bf16x8*)(Vb + (db * 32 + l31) * 128 + pcc * 16);
          o[db] = __builtin_amdgcn_mfma_f32_32x32x16_bf16(pa[k4], vf, o[db], 0, 0, 0);
        }
      __builtin_amdgcn_s_setprio(0);
    }
    __syncthreads();
    cur ^= 1;
  }
  float linv = 1.0f / l;
  float li[16];
  #pragma unroll
  for (int r = 0; r < 16; ++r)
    li[r] = __shfl(linv, (r & 3) + 8 * (r >> 2) + 4 * hh);
  #pragma unroll
  for (int db = 0; db < 4; ++db)
    #pragma unroll
    for (int r = 0; r < 16; ++r) {
      int qr = wq0 + (r & 3) + 8 * (r >> 2) + 4 * hh;
      Og[((long)b * SEQ + qr) * QSZ + h * HD + db * 32 + l31] = f2bf(o[db][r] * li[r]);
    }
}

// ---------------- launch -----------------------------------------------------
extern "C" void kernel_launch(void* const* d_in, const int* in_sizes, int n_in,
                              void* d_out, int out_size, void* d_ws, size_t ws_size,
                              hipStream_t stream) {
  const int*   positions = (const int*)d_in[0];
  const float* hidden    = (const float*)d_in[1];
  const float* Wqkv      = (const float*)d_in[2];
  const float* qnw       = (const float*)d_in[3];
  const float* knw       = (const float*)d_in[4];
  const float* Wo        = (const float*)d_in[5];
  float* out = (float*)d_out;
  char* ws = (char*)d_ws;
  const size_t MB = 1024 * 1024;
  u16* hbf   = (u16*)(ws + 0);        // 32MB: hidden bf16 (dead after gemm1)
  u16* WqkvT = (u16*)(ws + 32 * MB);  // 48MB: Wqkv^T bf16 (dead after gemm1)
  u16* qkvb  = (u16*)(ws + 80 * MB);  // 48MB: qkv bf16 (dead after ln_rope+v_transp)
  u16* q_arr = (u16*)(ws + 0);        // 32MB (aliases hbf)
  u16* k_arr = (u16*)(ws + 32 * MB);  //  8MB (aliases WqkvT[0:8M])
  u16* vt_arr= (u16*)(ws + 40 * MB);  //  8MB V^T [b][kvh][d][S]
  u16* WoT   = (u16*)(ws + 48 * MB);  // 32MB (aliases WqkvT[16M:48M])
  u16* Oarr  = (u16*)(ws + 80 * MB);  // 32MB (aliases qkvb[0:32M])

  const int GEMM_LDS = 3 * 49152;     // 144 KB
  (void)hipFuncSetAttribute((const void*)&gemm_bt2<u16>,
        hipFuncAttributeMaxDynamicSharedMemorySize, GEMM_LDS);
  (void)hipFuncSetAttribute((const void*)&gemm_bt2<float>,
        hipFuncAttributeMaxDynamicSharedMemorySize, GEMM_LDS);

  conv_f32_bf16<<<dim3(NTOK * HIDDEN / 8 / 256), 256, 0, stream>>>(hidden, hbf, NTOK * HIDDEN / 8);
  transp_f32_bf16<<<dim3(QKV_N / 32, HIDDEN / 32), 256, 0, stream>>>(Wqkv, WqkvT, HIDDEN, QKV_N);
  gemm_bt2<u16><<<dim3(QKV_N / 256, NTOK / 128), 512, GEMM_LDS, stream>>>(hbf, WqkvT, qkvb, QKV_N, HIDDEN);
  ln_rope<<<dim3(SEQ, NB), 512, 0, stream>>>(qkvb, positions, qnw, knw, q_arr, k_arr);
  v_transp<<<dim3(SEQ / 32, HD / 32, NB * NKV), 256, 0, stream>>>(qkvb, vt_arr);
  transp_f32_bf16<<<dim3(HIDDEN / 32, QSZ / 32), 256, 0, stream>>>(Wo, WoT, QSZ, HIDDEN);
  flash_attn2<<<dim3(512), 512, 0, stream>>>(q_arr, k_arr, vt_arr, Oarr);
  gemm_bt2<float><<<dim3(HIDDEN / 256, NTOK / 128), 512, GEMM_LDS, stream>>>(Oarr, WoT, out, HIDDEN, QSZ);
}